// Round 5
// baseline (183.385 us; speedup 1.0000x reference)
//
#include <hip/hip_runtime.h>
#include <stdint.h>

#define IMG 224
#define OUT_DIM 112
#define NCH 16

typedef __fp16 half2_t __attribute__((ext_vector_type(2)));
typedef __fp16 half8_t __attribute__((ext_vector_type(8)));
typedef float floatx4 __attribute__((ext_vector_type(4)));

// d_ws layout (uint32 words):
//   [0 .. 31]   : 16 x float2 (scale, shift) per channel (folds conv_b, mean, beta)
//   [32 .. 287] : weight table, 16 ch x 16 dwords; dword d = f16 pair (w'[2d], w'[2d+1])
//                 where w'[k] (k = r*6+c) = conv_w[r*5+c] if c<5 and k<30, else 0.
#define WS_WTAB 32

__global__ void prep_kernel(const float* __restrict__ conv_w,
                            const float* __restrict__ conv_b,
                            const float* __restrict__ gamma,
                            const float* __restrict__ beta,
                            const float* __restrict__ run_mean,
                            const float* __restrict__ run_var,
                            uint32_t* __restrict__ ws)
{
    int ch = threadIdx.x;
    if (ch >= NCH) return;
    float s = gamma[ch] * rsqrtf(run_var[ch] + 1e-5f);
    float t = fmaf(s, conv_b[ch] - run_mean[ch], beta[ch]);
    ((float2*)ws)[ch] = make_float2(s, t);

    const float* w = conv_w + ch * 25;
    uint32_t* wt = ws + WS_WTAB + ch * 16;
    for (int d = 0; d < 16; ++d) {
        float v[2];
        for (int e = 0; e < 2; ++e) {
            int k = 2 * d + e;
            int r = k / 6, c = k - 6 * r;
            v[e] = (k < 30 && c < 5) ? w[r * 5 + c] : 0.f;
        }
        half2_t h = __builtin_amdgcn_cvt_pkrtz(v[0], v[1]);
        wt[d] = __builtin_bit_cast(uint32_t, h);
    }
}

// XOR-swizzled im2col chunk address: pixel P's 64B vector lives as 4x16B chunks
// inside the 128B region of pixel-pair P>>1; swizzle spreads chunk->bank so both
// the build writes and the MFMA A-frag reads hit the 8-access/bank b128 floor.
__device__ __forceinline__ uint32_t imc_addr(uint32_t P, uint32_t q) {
    return (P >> 1) * 128u + ((((P & 1u) << 2) | q) ^ ((P >> 1) & 7u)) * 16u;
}

__global__ __launch_bounds__(256)
void conv_mfma(const float* __restrict__ x,
               const uint32_t* __restrict__ ws,
               float* __restrict__ out)
{
    __shared__ uint32_t imc[16384];   // 64 KB implicit-im2col: 1024 pixels x 64B

    const int tid = threadIdx.x;
    const int bx = blockIdx.x, by = blockIdx.y, b = blockIdx.z;
    const float* xb = x + (size_t)b * IMG * IMG;

    // ---------- build phase: 4 conv pixels (2x2 quad) per thread ----------
    const int px = tid & 15, py = tid >> 4;
    const int gy0 = by * 32 + 2 * py - 2;   // topmost input row of the 6x8 patch
    const int gx0 = bx * 32 + 2 * px - 2;   // leftmost input col

    float f[6][8];
    if (bx >= 1 && bx <= 5 && by >= 1 && by <= 5) {
        // interior: all 6x8 in-bounds, aligned float2 loads
        #pragma unroll
        for (int r = 0; r < 6; ++r) {
            const float* rowp = xb + (gy0 + r) * IMG + gx0;
            #pragma unroll
            for (int j = 0; j < 4; ++j) {
                float2 v = *(const float2*)(rowp + 2 * j);
                f[r][2 * j] = v.x; f[r][2 * j + 1] = v.y;
            }
        }
    } else {
        #pragma unroll
        for (int r = 0; r < 6; ++r) {
            int gy = gy0 + r;
            #pragma unroll
            for (int j = 0; j < 8; ++j) {
                int gx = gx0 + j;
                f[r][j] = ((unsigned)gy < IMG && (unsigned)gx < IMG)
                        ? xb[gy * IMG + gx] : 0.f;
            }
        }
    }

    // sliding f16 pairs per patch row: [0..2]=even-pixel pairs, [3..5]=odd-pixel
    uint32_t pr[6][6];
    #pragma unroll
    for (int r = 0; r < 6; ++r) {
        pr[r][0] = __builtin_bit_cast(uint32_t, __builtin_amdgcn_cvt_pkrtz(f[r][0], f[r][1]));
        pr[r][1] = __builtin_bit_cast(uint32_t, __builtin_amdgcn_cvt_pkrtz(f[r][2], f[r][3]));
        pr[r][2] = __builtin_bit_cast(uint32_t, __builtin_amdgcn_cvt_pkrtz(f[r][4], f[r][5]));
        pr[r][3] = __builtin_bit_cast(uint32_t, __builtin_amdgcn_cvt_pkrtz(f[r][1], f[r][2]));
        pr[r][4] = __builtin_bit_cast(uint32_t, __builtin_amdgcn_cvt_pkrtz(f[r][3], f[r][4]));
        pr[r][5] = __builtin_bit_cast(uint32_t, __builtin_amdgcn_cvt_pkrtz(f[r][5], f[r][6]));
    }

    #pragma unroll
    for (int dy = 0; dy < 2; ++dy) {
        #pragma unroll
        for (int dx = 0; dx < 2; ++dx) {
            const uint32_t P = (2 * py + dy) * 32 + 2 * px + dx;
            const int o = 3 * dx;
            // k = r*6+c patch vector, chunks of 8 halves (4 dwords)
            uint4 c0 = {pr[dy  ][o], pr[dy  ][o+1], pr[dy  ][o+2], pr[dy+1][o]};
            uint4 c1 = {pr[dy+1][o+1], pr[dy+1][o+2], pr[dy+2][o], pr[dy+2][o+1]};
            uint4 c2 = {pr[dy+2][o+2], pr[dy+3][o], pr[dy+3][o+1], pr[dy+3][o+2]};
            uint4 c3 = {pr[dy+4][o], pr[dy+4][o+1], pr[dy+4][o+2], 0u};
            *(uint4*)((char*)imc + imc_addr(P, 0)) = c0;
            *(uint4*)((char*)imc + imc_addr(P, 1)) = c1;
            *(uint4*)((char*)imc + imc_addr(P, 2)) = c2;
            *(uint4*)((char*)imc + imc_addr(P, 3)) = c3;
        }
    }

    // per-lane constants (independent of barrier): B-frag + BN constants
    const int lane = tid & 63;
    const int n = lane & 15;          // channel (B/D col) AND pixel m (A row)
    const int q = lane >> 4;          // k-chunk (A/B) AND output x-group (D)
    uint4 bw = ((const uint4*)(ws + WS_WTAB))[n * 4 + q];
    half8_t bfrag = __builtin_bit_cast(half8_t, bw);
    float2 st = ((const float2*)ws)[n];

    __syncthreads();

    // ---------- MFMA phase: 8 row-pairs per wave ----------
    const int w = tid >> 6;
    float* outb = out + (size_t)b * NCH * (OUT_DIM * OUT_DIM)
                      + (size_t)n * (OUT_DIM * OUT_DIM);

    #pragma unroll
    for (int i = 0; i < 8; ++i) {
        const int gp = w * 8 + i;
        const int Y = gp >> 1, xh = gp & 1;         // pooled row, x-half
        const uint32_t P0 = 64u * Y + 16u * xh + (uint32_t)n;  // conv row 2Y
        uint4 a0w = *(const uint4*)((const char*)imc + imc_addr(P0, q));
        uint4 a1w = *(const uint4*)((const char*)imc + imc_addr(P0 + 32u, q));
        floatx4 z = {0.f, 0.f, 0.f, 0.f};
        floatx4 d0 = __builtin_amdgcn_mfma_f32_16x16x32_f16(
            __builtin_bit_cast(half8_t, a0w), bfrag, z, 0, 0, 0);
        floatx4 d1 = __builtin_amdgcn_mfma_f32_16x16x32_f16(
            __builtin_bit_cast(half8_t, a1w), bfrag, z, 0, 0, 0);
        // y-pool across the two row-MFMAs, x-pool across reg pairs (all intra-lane)
        float c0 = fmaxf(d0[0], d1[0]);
        float c1 = fmaxf(d0[1], d1[1]);
        float c2 = fmaxf(d0[2], d1[2]);
        float c3 = fmaxf(d0[3], d1[3]);
        float o0 = fmaxf(fmaf(fmaxf(c0, c1), st.x, st.y), 0.f);
        float o1 = fmaxf(fmaf(fmaxf(c2, c3), st.x, st.y), 0.f);
        const int gyp = by * 16 + Y;
        const int gxp = bx * 16 + xh * 8 + 2 * q;
        *(float2*)(outb + gyp * OUT_DIM + gxp) = make_float2(o0, o1);
    }
}

extern "C" void kernel_launch(void* const* d_in, const int* in_sizes, int n_in,
                              void* d_out, int out_size, void* d_ws, size_t ws_size,
                              hipStream_t stream) {
    const float* x        = (const float*)d_in[0];
    const float* conv_w   = (const float*)d_in[1];
    const float* conv_b   = (const float*)d_in[2];
    const float* gamma    = (const float*)d_in[3];
    const float* beta     = (const float*)d_in[4];
    const float* run_mean = (const float*)d_in[5];
    const float* run_var  = (const float*)d_in[6];
    float* out = (float*)d_out;
    uint32_t* ws = (uint32_t*)d_ws;

    prep_kernel<<<1, 64, 0, stream>>>(conv_w, conv_b, gamma, beta, run_mean, run_var, ws);

    dim3 grid(7, 7, 128);
    dim3 block(256);
    conv_mfma<<<grid, block, 0, stream>>>(x, ws, out);
}